// Round 1
// baseline (806.019 us; speedup 1.0000x reference)
//
#include <hip/hip_runtime.h>

// DynamicFilterLayer2D: out[b,c,h,w] = sum_{i,j in 3x3} xpad[b,c,h+i,w+j] * f[b,c,i*3+j,h,w]
// B=8, C=32, H=256, W=256, K=3, PAD=1. All float32.
// Memory-bound: filters (576 MiB) stream once; x (64 MiB) has 9x spatial reuse (L1/L2).

constexpr int Bc = 8;
constexpr int Cc = 32;
constexpr int Hc = 256;
constexpr int Wc = 256;
constexpr int HW = Hc * Wc;
constexpr int W4 = Wc / 4;

__global__ __launch_bounds__(256) void dyn_filter_kernel(
    const float* __restrict__ x,
    const float* __restrict__ f,
    float* __restrict__ out)
{
    int idx = blockIdx.x * blockDim.x + threadIdx.x;
    if (idx >= Bc * Cc * Hc * W4) return;

    // idx = ((bc * H) + h) * W4 + w4 ; each wave (64 lanes) covers one full row.
    int w4 = idx & (W4 - 1);          // W4 = 64
    int t  = idx >> 6;
    int h  = t & (Hc - 1);            // H = 256
    int bc = t >> 8;
    int w0 = w4 << 2;

    const float* xplane = x + (size_t)bc * HW;
    const float* fbase  = f + (size_t)bc * 9 * HW + (size_t)h * Wc + w0;

    float4 acc = make_float4(0.f, 0.f, 0.f, 0.f);

#pragma unroll
    for (int di = 0; di < 3; ++di) {
        int hy = h + di - 1;
        if (hy < 0 || hy >= Hc) continue;   // wave-uniform branch (h uniform per wave)
        const float* xrow = xplane + (size_t)hy * Wc + w0;
        float4 mid  = *(const float4*)(xrow);
        float  left  = (w0 > 0)      ? xrow[-1] : 0.f;
        float  right = (w0 + 4 < Wc) ? xrow[4]  : 0.f;

        // tap j=0: window shifted left by 1 -> (left, mid.x, mid.y, mid.z)
        {
            float4 ff = *(const float4*)(fbase + (size_t)(di * 3 + 0) * HW);
            acc.x += left  * ff.x;
            acc.y += mid.x * ff.y;
            acc.z += mid.y * ff.z;
            acc.w += mid.z * ff.w;
        }
        // tap j=1: centered -> mid
        {
            float4 ff = *(const float4*)(fbase + (size_t)(di * 3 + 1) * HW);
            acc.x += mid.x * ff.x;
            acc.y += mid.y * ff.y;
            acc.z += mid.z * ff.z;
            acc.w += mid.w * ff.w;
        }
        // tap j=2: shifted right by 1 -> (mid.y, mid.z, mid.w, right)
        {
            float4 ff = *(const float4*)(fbase + (size_t)(di * 3 + 2) * HW);
            acc.x += mid.y * ff.x;
            acc.y += mid.z * ff.y;
            acc.z += mid.w * ff.z;
            acc.w += right * ff.w;
        }
    }

    *(float4*)(out + (size_t)bc * HW + (size_t)h * Wc + w0) = acc;
}

extern "C" void kernel_launch(void* const* d_in, const int* in_sizes, int n_in,
                              void* d_out, int out_size, void* d_ws, size_t ws_size,
                              hipStream_t stream) {
    const float* x = (const float*)d_in[0];
    const float* f = (const float*)d_in[1];
    float* out = (float*)d_out;

    int total = Bc * Cc * Hc * W4;           // 4,194,304 threads
    int block = 256;
    int grid  = (total + block - 1) / block; // 16384 blocks
    dyn_filter_kernel<<<grid, block, 0, stream>>>(x, f, out);
}

// Round 3
// 789.841 us; speedup vs baseline: 1.0205x; 1.0205x over previous
//
#include <hip/hip_runtime.h>

// DynamicFilterLayer2D: out[b,c,h,w] = sum_{i,j in 3x3} xpad[b,c,h+i-1,w+j-1] * f[b,c,i*3+j,h,w]
// B=8, C=32, H=256, W=256, K=3, PAD=1. All float32.
// Memory-bound (filters: 576 MiB streamed once). Strategy:
//  - one wave = one full row pair (64 lanes x 4 floats = 256 = W)
//  - 2 output rows per thread: x rows h-1..h+2 loaded once, 22 float4 VMEM/thread (MLP)
//  - halo columns via __shfl from neighbor lanes (lane 0/63 edges == zero-pad)
//  - nontemporal loads for filters, nontemporal stores for out (single-use data)
// NOTE: __builtin_nontemporal_* requires a native clang vector type, not HIP's float4 struct.

typedef float v4f __attribute__((ext_vector_type(4)));

constexpr int Bc = 8;
constexpr int Cc = 32;
constexpr int Hc = 256;
constexpr int Wc = 256;
constexpr int HW = Hc * Wc;
constexpr int W4 = Wc / 4;   // 64
constexpr int H2 = Hc / 2;   // 128

__global__ __launch_bounds__(256) void dyn_filter_kernel(
    const float* __restrict__ x,
    const float* __restrict__ f,
    float* __restrict__ out)
{
    int idx  = blockIdx.x * blockDim.x + threadIdx.x;
    int lane = threadIdx.x & 63;

    int w4 = idx & (W4 - 1);
    int t  = idx >> 6;
    int hh = t & (H2 - 1);
    int bc = t >> 7;
    int h0 = hh << 1;          // first of the two output rows
    int w0 = w4 << 2;

    // ---- load 4 x rows (h0-1 .. h0+2), zero for out-of-range (wave-uniform) ----
    const float* xrowbase = x + (size_t)bc * HW + w0;
    v4f r[4];
#pragma unroll
    for (int k = 0; k < 4; ++k) {
        int hy = h0 - 1 + k;
        if (hy >= 0 && hy < Hc)
            r[k] = *(const v4f*)(xrowbase + (size_t)hy * Wc);
        else
            r[k] = (v4f)(0.f);
    }

    // ---- column halos via shuffle: left = prev lane's .w, right = next lane's .x ----
    float lft[4], rgt[4];
#pragma unroll
    for (int k = 0; k < 4; ++k) {
        lft[k] = __shfl_up(r[k].w, 1);
        rgt[k] = __shfl_down(r[k].x, 1);
        if (lane == 0)  lft[k] = 0.f;   // zero pad at w = -1
        if (lane == 63) rgt[k] = 0.f;   // zero pad at w = 256
    }

    const float* fbase = f + (size_t)bc * 9 * HW + (size_t)h0 * Wc + w0;

    v4f a0 = (v4f)(0.f);
    v4f a1 = (v4f)(0.f);

#pragma unroll
    for (int di = 0; di < 3; ++di) {
        v4f   xa = r[di];        // x row for output row h0
        v4f   xb = r[di + 1];    // x row for output row h0+1
        float la = lft[di],     lb = lft[di + 1];
        float ra = rgt[di],     rb = rgt[di + 1];
#pragma unroll
        for (int dj = 0; dj < 3; ++dj) {
            const float* fp = fbase + (size_t)(di * 3 + dj) * HW;
            v4f f0 = __builtin_nontemporal_load((const v4f*)fp);
            v4f f1 = __builtin_nontemporal_load((const v4f*)(fp + Wc));

            v4f wa, wb;
            if (dj == 0) {        // window cols w-1..w+2
                wa = (v4f){la,   xa.x, xa.y, xa.z};
                wb = (v4f){lb,   xb.x, xb.y, xb.z};
            } else if (dj == 1) { // centered
                wa = xa;
                wb = xb;
            } else {              // window cols w+1..w+4
                wa = (v4f){xa.y, xa.z, xa.w, ra};
                wb = (v4f){xb.y, xb.z, xb.w, rb};
            }
            a0 += wa * f0;
            a1 += wb * f1;
        }
    }

    float* op = out + (size_t)bc * HW + (size_t)h0 * Wc + w0;
    __builtin_nontemporal_store(a0, (v4f*)op);
    __builtin_nontemporal_store(a1, (v4f*)(op + Wc));
}

extern "C" void kernel_launch(void* const* d_in, const int* in_sizes, int n_in,
                              void* d_out, int out_size, void* d_ws, size_t ws_size,
                              hipStream_t stream) {
    const float* x = (const float*)d_in[0];
    const float* f = (const float*)d_in[1];
    float* out = (float*)d_out;

    int total = Bc * Cc * H2 * W4;           // 2,097,152 threads
    int block = 256;
    int grid  = (total + block - 1) / block; // 8192 blocks
    dyn_filter_kernel<<<grid, block, 0, stream>>>(x, f, out);
}